// Round 7
// baseline (2664.594 us; speedup 1.0000x reference)
//
#include <hip/hip_runtime.h>
#include <hip/hip_bf16.h>
#include <stdint.h>
#include <math.h>

#define BATCH 16384
#define DIN   784
#define HID   4096
#define DOUT  10
#define KW    128            // HID/32 words per row
#define KP    1600           // split-K: hi[0,784) lo[784,1568) pad[1568,1600)
#define CAP   1048576
#define BN_EPS 1e-5
#define TAU   0.05f          // verified R5/R6: |h_mfma - h_chain| << TAU

// ---------------- workspace layout (bytes) ----------------
constexpr size_t SZ_BITS   = (size_t)BATCH * KW * 4;     // 8 MB
constexpr size_t OFF_BITS1 = 0;
constexpr size_t OFF_BITS2 = OFF_BITS1 + SZ_BITS;
constexpr size_t OFF_W2B   = OFF_BITS2 + SZ_BITS;
constexpr size_t OFF_W3B   = OFF_W2B + (size_t)HID * KW * 4;
constexpr size_t OFF_W4B   = OFF_W3B + (size_t)HID * KW * 4;
constexpr size_t OFF_W1B   = OFF_W4B + 8192;             // 4096 rows x 128 B
constexpr size_t OFF_CNT   = OFF_W1B + (size_t)HID * 128;
constexpr size_t OFF_LIST  = OFF_CNT + 256;
constexpr size_t OFF_XHL   = (OFF_LIST + (size_t)CAP * 4 + 255) & ~(size_t)255;
// Xhl: 16384*1600*2 = 52.4 MB

typedef __attribute__((ext_vector_type(8))) short frag8;   // 8 bf16 (4 VGPRs)
typedef __attribute__((ext_vector_type(4))) float f32x4;   // MFMA accum

__device__ __forceinline__ unsigned short f2bf_bits(float x) {
  __hip_bfloat16 h = __float2bfloat16(x);   // RNE
  return *reinterpret_cast<unsigned short*>(&h);
}
__device__ __forceinline__ float bf2f(unsigned short b) {
  union { unsigned int u; float f; } c;
  c.u = ((unsigned int)b) << 16;
  return c.f;
}

// byte of packed sign bits -> frag8 of (+-1) bf16; bit e -> elem e; bit=1 -> +1
__device__ __forceinline__ frag8 expand_signs(uint32_t wb) {
  uint32_t nw = ~wb;
  union { uint32_t u[4]; frag8 f; } r;
#pragma unroll
  for (int j = 0; j < 4; ++j)
    r.u[j] = 0x3F803F80u | (((nw >> (2 * j)) & 1u) << 15)
                         | (((nw >> (2 * j + 1)) & 1u) << 31);
  return r.f;
}

__global__ void zero_cnt_kernel(int* cnt) {
  if (threadIdx.x == 0) *cnt = 0;
}

// binarize row-major contiguous fp32 -> bitmask words (for w2/w3/w4)
__global__ __launch_bounds__(256) void binarize_kernel(
    const float* __restrict__ w, uint32_t* __restrict__ bits, int nwords) {
  int t = blockIdx.x * 256 + threadIdx.x;
  if (t >= nwords) return;
  const float* p = w + (size_t)t * 32;
  uint32_t word = 0;
#pragma unroll
  for (int q = 0; q < 8; ++q) {
    float4 v = *(const float4*)(p + q * 4);
    word |= (uint32_t)(v.x >= 0.f) << (4 * q + 0);
    word |= (uint32_t)(v.y >= 0.f) << (4 * q + 1);
    word |= (uint32_t)(v.z >= 0.f) << (4 * q + 2);
    word |= (uint32_t)(v.w >= 0.f) << (4 * q + 3);
  }
  bits[t] = word;
}

// W1 (4096x784) -> sign bits, row stride 32 words (128 B)
__global__ __launch_bounds__(256) void binarize_w1_kernel(
    const float* __restrict__ w, uint32_t* __restrict__ bits) {
  int idx = blockIdx.x * 256 + threadIdx.x;   // 4096*25 = 102400
  if (idx >= HID * 25) return;
  int row = idx / 25, wq = idx - row * 25;
  int kbase = wq * 32;
  int nv = (kbase + 32 <= DIN) ? 32 : (DIN - kbase);   // 32 or 16
  const float* p = w + (size_t)row * DIN + kbase;
  uint32_t word = 0;
  for (int e = 0; e < nv; ++e)
    word |= (uint32_t)(p[e] >= 0.f) << e;
  bits[(size_t)row * 32 + wq] = word;
}

// X -> bf16 hi/lo split, row layout [hi 0..783 | lo 784..1567 | zero pad ..1599]
__global__ __launch_bounds__(256) void convert_x_kernel(
    const float* __restrict__ X, short* __restrict__ Xhl) {
  int idx = blockIdx.x * 256 + threadIdx.x;      // BATCH*50 = 819200 exact
  int row = idx / 50, kq = idx - row * 50;
  short* orow = Xhl + (size_t)row * KP;
  if (kq < 49) {
    const float* p = X + (size_t)row * DIN + kq * 16;
    short hi[16], lo[16];
#pragma unroll
    for (int q = 0; q < 4; ++q) {
      float4 v = *(const float4*)(p + q * 4);
      float vv[4] = {v.x, v.y, v.z, v.w};
#pragma unroll
      for (int e = 0; e < 4; ++e) {
        unsigned short h = f2bf_bits(vv[e]);
        hi[q * 4 + e] = (short)h;
        lo[q * 4 + e] = (short)f2bf_bits(vv[e] - bf2f(h));
      }
    }
    *(uint4*)(orow + kq * 16)           = *(uint4*)&hi[0];
    *(uint4*)(orow + kq * 16 + 8)       = *(uint4*)&hi[8];
    *(uint4*)(orow + 784 + kq * 16)     = *(uint4*)&lo[0];
    *(uint4*)(orow + 784 + kq * 16 + 8) = *(uint4*)&lo[8];
  } else {
    uint4 z = {0, 0, 0, 0};
#pragma unroll
    for (int q = 0; q < 4; ++q) *(uint4*)(orow + 1568 + q * 8) = z;
  }
}

// Layer 1: bf16 MFMA, NO LDS / NO K-loop barriers.
// Block tile 128(M) x 256(N), 4 waves (2x2), wave tile 64x128.
// A frags: direct global->VGPR dwordx4 (layout == MFMA A layout).
// B frags: 1 byte of packed W1 signs per frag per lane, expanded in-register.
// XCD swizzle: xcd = bid&7 owns rb stripe -> X fetched ~once chip-wide.
__global__ __launch_bounds__(256) void gemm1_mfma_kernel(
    const short* __restrict__ Xhl, const uint8_t* __restrict__ W1b,
    const float* __restrict__ Bv, const float* __restrict__ Gv,
    const float* __restrict__ BEv, const float* __restrict__ Mv,
    const float* __restrict__ Vv,
    uint32_t* __restrict__ bits_out, int* __restrict__ cnt,
    uint32_t* __restrict__ list) {
  __shared__ unsigned short PW16[128 * 16];   // 4 KB packed sign bits

  const int tid = threadIdx.x;
  const int bid = blockIdx.x;                 // 2048 blocks
  const int xcd = bid & 7;
  const int t   = bid >> 3;                   // 0..255
  const int cb  = t & 15;                     // 0..15  (N/256)
  const int rb  = xcd * 16 + (t >> 4);        // 0..127 (M/128)
  const int m0 = rb * 128, n0 = cb * 256;

  const int lane = tid & 63;
  const int wv = tid >> 6;                    // 0..3
  const int wm = wv & 1, wn = wv >> 1;
  const int l15 = lane & 15, l4 = lane >> 4;

  f32x4 acc[4][8];
#pragma unroll
  for (int i = 0; i < 4; ++i)
#pragma unroll
    for (int j = 0; j < 8; ++j) acc[i][j] = (f32x4){0.f, 0.f, 0.f, 0.f};

  // A row pointers (per mf): row = m0 + wm*64 + mf*16 + l15
  const short* arow[4];
#pragma unroll
  for (int mf = 0; mf < 4; ++mf)
    arow[mf] = Xhl + (size_t)(m0 + wm * 64 + mf * 16 + l15) * KP;
  // B byte base (per nf): row n = n0 + wn*128 + nf*16 + l15, stride 128 B
  const uint8_t* brow[8];
#pragma unroll
  for (int nf = 0; nf < 8; ++nf)
    brow[nf] = W1b + (size_t)(n0 + wn * 128 + nf * 16 + l15) * 128;

  for (int s = 0; s < 25; ++s) {
    // byte offsets for the two K=32 halves (8-aligned; regions never straddle)
    int bo[2];
#pragma unroll
    for (int h = 0; h < 2; ++h) {
      int kg = s * 64 + h * 32 + l4 * 8;
      int k2 = (kg >= 1568) ? 0 : (kg >= 784 ? kg - 784 : kg);
      bo[h] = k2 >> 3;
    }
    uint32_t wb[2][8];
#pragma unroll
    for (int h = 0; h < 2; ++h)
#pragma unroll
      for (int nf = 0; nf < 8; ++nf)
        wb[h][nf] = brow[nf][bo[h]];
    frag8 af[4][2];
#pragma unroll
    for (int mf = 0; mf < 4; ++mf)
#pragma unroll
      for (int h = 0; h < 2; ++h)
        af[mf][h] = *(const frag8*)(arow[mf] + s * 64 + h * 32 + l4 * 8);
#pragma unroll
    for (int h = 0; h < 2; ++h) {
      frag8 bf[8];
#pragma unroll
      for (int nf = 0; nf < 8; ++nf) bf[nf] = expand_signs(wb[h][nf]);
#pragma unroll
      for (int mf = 0; mf < 4; ++mf)
#pragma unroll
        for (int nf = 0; nf < 8; ++nf)
          acc[mf][nf] = __builtin_amdgcn_mfma_f32_16x16x32_bf16(
              af[mf][h], bf[nf], acc[mf][nf], 0, 0, 0);
    }
  }

  // ---- epilogue: BN sign + borderline flag + ballot pack (R5/R6-verified) ----
#pragma unroll
  for (int nf = 0; nf < 8; ++nf) {
    const int gj = n0 + wn * 128 + nf * 16 + l15;
    const float  bj = Bv[gj];
    const double scale = (double)Gv[gj] / sqrt((double)Vv[gj] + BN_EPS);
    const double mj = (double)Mv[gj], bej = (double)BEv[gj];
    const double thr = (double)TAU * fabs(scale);
#pragma unroll
    for (int mf = 0; mf < 4; ++mf) {
#pragma unroll
      for (int r = 0; r < 4; ++r) {
        const int row_l = wm * 64 + mf * 16 + l4 * 4 + r;
        float hb = acc[mf][nf][r] + bj;          // f32, matches chain epilogue
        double bnd = ((double)hb - mj) * scale + bej;
        unsigned int bit = (bnd >= 0.0) ? 1u : 0u;
        unsigned long long mask = __ballot(bit);
        if (l15 == 0)
          PW16[row_l * 16 + wn * 8 + nf] = (unsigned short)(mask >> (l4 * 16));
        if (fabs(bnd) < thr) {
          int pos = atomicAdd(cnt, 1);
          if (pos < CAP)
            list[pos] = (uint32_t)((m0 + row_l) * HID + gj);
        }
      }
    }
  }
  __syncthreads();
  for (int t2 = tid; t2 < 1024; t2 += 256) {
    int row = t2 >> 3, wc = t2 & 7;
    uint32_t word = (uint32_t)PW16[row * 16 + wc * 2] |
                    ((uint32_t)PW16[row * 16 + wc * 2 + 1] << 16);
    bits_out[(size_t)(m0 + row) * KW + cb * 8 + wc] = word;
  }
}

// Recompute flagged layer-1 elements with the reference's EXACT semantics:
// sequential ascending-k single f32 FMA chain, then h + b in f32, then BN.
__global__ __launch_bounds__(256) void fixup_chain_kernel(
    const float* __restrict__ X, const float* __restrict__ W,
    const float* __restrict__ Bv, const float* __restrict__ Gv,
    const float* __restrict__ BEv, const float* __restrict__ Mv,
    const float* __restrict__ Vv,
    uint32_t* __restrict__ bits1, const int* __restrict__ cnt,
    const uint32_t* __restrict__ list) {
  int n = *cnt;
  if (n > CAP) n = CAP;
  for (int idx = blockIdx.x * 256 + threadIdx.x; idx < n;
       idx += gridDim.x * 256) {
    uint32_t code = list[idx];
    int i = code >> 12;
    int j = code & (HID - 1);
    const float* xr = X + (size_t)i * DIN;
    const float* wr = W + (size_t)j * DIN;
    float h = 0.f;
    for (int k = 0; k < DIN; k += 4) {     // strictly ascending k
      float4 xv = *(const float4*)(xr + k);
      float4 wv = *(const float4*)(wr + k);
      h = fmaf(xv.x, (wv.x >= 0.f) ? 1.f : -1.f, h);
      h = fmaf(xv.y, (wv.y >= 0.f) ? 1.f : -1.f, h);
      h = fmaf(xv.z, (wv.z >= 0.f) ? 1.f : -1.f, h);
      h = fmaf(xv.w, (wv.w >= 0.f) ? 1.f : -1.f, h);
    }
    float hb = h + Bv[j];
    double scale = (double)Gv[j] / sqrt((double)Vv[j] + BN_EPS);
    double bnd = ((double)hb - (double)Mv[j]) * scale + (double)BEv[j];
    uint32_t bit = (bnd >= 0.0) ? 1u : 0u;
    uint32_t* wpw = &bits1[(size_t)i * KW + (j >> 5)];
    uint32_t cur = (*wpw >> (j & 31)) & 1u;
    if (cur != bit) atomicXor(wpw, 1u << (j & 31));
  }
}

// Layers 2/3: +-1 x +-1 GEMM via XOR+popcount (exact). BN -> sign bits out.
// XCD swizzle: each XCD owns an rb stripe; W-bits (2 MB) stay L2-resident.
__global__ __launch_bounds__(256) void bitgemm_kernel(
    const uint32_t* __restrict__ Abits, const uint32_t* __restrict__ Wbits,
    const float* __restrict__ Bv, const float* __restrict__ Gv,
    const float* __restrict__ BEv, const float* __restrict__ Mv,
    const float* __restrict__ Vv, uint32_t* __restrict__ bits_out) {
  __shared__ uint32_t As[16 * 128];
  __shared__ uint32_t Bs[16 * 128];
  __shared__ unsigned int PW[128 * 4];

  const int tid = threadIdx.x;
  const int bid = blockIdx.x;                 // 4096 blocks
  const int xcd = bid & 7;
  const int t   = bid >> 3;                   // 0..511
  const int cb  = t & 31;
  const int rb  = xcd * 16 + (t >> 5);        // 0..127
  const int m0 = rb * 128, n0 = cb * 128;
  const int tx = tid & 15, ty = tid >> 4;

  int acc[8][8];
#pragma unroll
  for (int r = 0; r < 8; ++r)
#pragma unroll
    for (int c = 0; c < 8; ++c) acc[r][c] = 0;

  const int sr = tid >> 1;
  const int sk = (tid & 1) * 8;
  const uint32_t* arow = Abits + (size_t)(m0 + sr) * KW + sk;
  const uint32_t* wrow = Wbits + (size_t)(n0 + sr) * KW + sk;

  for (int w0 = 0; w0 < KW; w0 += 16) {
    uint4 a0 = *(const uint4*)(arow + w0);
    uint4 a1 = *(const uint4*)(arow + w0 + 4);
    uint4 b0 = *(const uint4*)(wrow + w0);
    uint4 b1 = *(const uint4*)(wrow + w0 + 4);
    __syncthreads();
    As[(sk + 0) * 128 + sr] = a0.x;  As[(sk + 1) * 128 + sr] = a0.y;
    As[(sk + 2) * 128 + sr] = a0.z;  As[(sk + 3) * 128 + sr] = a0.w;
    As[(sk + 4) * 128 + sr] = a1.x;  As[(sk + 5) * 128 + sr] = a1.y;
    As[(sk + 6) * 128 + sr] = a1.z;  As[(sk + 7) * 128 + sr] = a1.w;
    Bs[(sk + 0) * 128 + sr] = b0.x;  Bs[(sk + 1) * 128 + sr] = b0.y;
    Bs[(sk + 2) * 128 + sr] = b0.z;  Bs[(sk + 3) * 128 + sr] = b0.w;
    Bs[(sk + 4) * 128 + sr] = b1.x;  Bs[(sk + 5) * 128 + sr] = b1.y;
    Bs[(sk + 6) * 128 + sr] = b1.z;  Bs[(sk + 7) * 128 + sr] = b1.w;
    __syncthreads();
#pragma unroll
    for (int kk = 0; kk < 16; ++kk) {
      uint32_t a[8], b[8];
      *(uint4*)&a[0] = *(const uint4*)&As[kk * 128 + ty * 8];
      *(uint4*)&a[4] = *(const uint4*)&As[kk * 128 + ty * 8 + 4];
      *(uint4*)&b[0] = *(const uint4*)&Bs[kk * 128 + tx * 8];
      *(uint4*)&b[4] = *(const uint4*)&Bs[kk * 128 + tx * 8 + 4];
#pragma unroll
      for (int r = 0; r < 8; ++r)
#pragma unroll
        for (int c = 0; c < 8; ++c)
          acc[r][c] += __popc(a[r] ^ b[c]);
    }
  }

  uint32_t bm[8];
#pragma unroll
  for (int r = 0; r < 8; ++r) bm[r] = 0;
  for (int c = 0; c < 8; ++c) {
    const int j = n0 + tx * 8 + c;
    const double scale = (double)Gv[j] / sqrt((double)Vv[j] + BN_EPS);
    const double mj = (double)Mv[j], bej = (double)BEv[j], bj = (double)Bv[j];
#pragma unroll
    for (int r = 0; r < 8; ++r) {
      double h = (double)(HID - 2 * acc[r][c]) + bj;   // exact integer dot
      double bnd = (h - mj) * scale + bej;
      bm[r] |= (uint32_t)(bnd >= 0.0) << c;
    }
  }
  for (int t2 = tid; t2 < 512; t2 += 256) PW[t2] = 0u;
  __syncthreads();
#pragma unroll
  for (int r = 0; r < 8; ++r)
    atomicOr(&PW[(ty * 8 + r) * 4 + (tx >> 2)], bm[r] << (8 * (tx & 3)));
  __syncthreads();
  for (int w = tid; w < 512; w += 256) {
    int row = w >> 2, wc = w & 3;
    bits_out[(size_t)(m0 + row) * KW + (n0 >> 5) + wc] = PW[row * 4 + wc];
  }
}

// Layer 4 (10 outputs) + log_softmax. One wave per batch row.
__global__ __launch_bounds__(256) void final_kernel(
    const uint32_t* __restrict__ xbits, const uint32_t* __restrict__ w4b,
    const float* __restrict__ b4, float* __restrict__ out) {
  __shared__ uint32_t Ws[DOUT * KW];   // 5 KB
  const int tid = threadIdx.x;
  for (int t = tid; t < DOUT * KW; t += 256) Ws[t] = w4b[t];
  __syncthreads();
  const int lane = tid & 63;
  const int i = blockIdx.x * 4 + (tid >> 6);
  const uint32_t x0 = xbits[(size_t)i * KW + lane];
  const uint32_t x1 = xbits[(size_t)i * KW + 64 + lane];
  int cnt[DOUT];
#pragma unroll
  for (int j = 0; j < DOUT; ++j)
    cnt[j] = __popc(x0 ^ Ws[j * KW + lane]) + __popc(x1 ^ Ws[j * KW + 64 + lane]);
#pragma unroll
  for (int j = 0; j < DOUT; ++j)
#pragma unroll
    for (int off = 32; off; off >>= 1) cnt[j] += __shfl_xor(cnt[j], off);
  double logit[DOUT];
  double mx = -1e300;
#pragma unroll
  for (int j = 0; j < DOUT; ++j) {
    logit[j] = (double)(HID - 2 * cnt[j]) + (double)b4[j];
    mx = fmax(mx, logit[j]);
  }
  double s = 0.0;
#pragma unroll
  for (int j = 0; j < DOUT; ++j) s += exp(logit[j] - mx);
  double lse = log(s) + mx;
  if (lane < DOUT)
    out[(size_t)i * DOUT + lane] = (float)(logit[lane] - lse);
}

extern "C" void kernel_launch(void* const* d_in, const int* in_sizes, int n_in,
                              void* d_out, int out_size, void* d_ws, size_t ws_size,
                              hipStream_t stream) {
  const float* x   = (const float*)d_in[0];
  const float* w1  = (const float*)d_in[1];
  const float* b1  = (const float*)d_in[2];
  const float* g1  = (const float*)d_in[3];
  const float* be1 = (const float*)d_in[4];
  const float* m1  = (const float*)d_in[5];
  const float* v1  = (const float*)d_in[6];
  const float* w2  = (const float*)d_in[7];
  const float* b2  = (const float*)d_in[8];
  const float* g2  = (const float*)d_in[9];
  const float* be2 = (const float*)d_in[10];
  const float* m2  = (const float*)d_in[11];
  const float* v2  = (const float*)d_in[12];
  const float* w3  = (const float*)d_in[13];
  const float* b3  = (const float*)d_in[14];
  const float* g3  = (const float*)d_in[15];
  const float* be3 = (const float*)d_in[16];
  const float* m3  = (const float*)d_in[17];
  const float* v3  = (const float*)d_in[18];
  const float* w4  = (const float*)d_in[19];
  const float* b4  = (const float*)d_in[20];

  char* ws = (char*)d_ws;
  uint32_t* bits1 = (uint32_t*)(ws + OFF_BITS1);
  uint32_t* bits2 = (uint32_t*)(ws + OFF_BITS2);
  uint32_t* w2b   = (uint32_t*)(ws + OFF_W2B);
  uint32_t* w3b   = (uint32_t*)(ws + OFF_W3B);
  uint32_t* w4b   = (uint32_t*)(ws + OFF_W4B);
  uint32_t* w1b   = (uint32_t*)(ws + OFF_W1B);
  int*      cnt   = (int*)(ws + OFF_CNT);
  uint32_t* list  = (uint32_t*)(ws + OFF_LIST);
  short*    xhl   = (short*)(ws + OFF_XHL);
  float*    out   = (float*)d_out;

  zero_cnt_kernel<<<1, 64, 0, stream>>>(cnt);
  binarize_kernel<<<(HID * KW + 255) / 256, 256, 0, stream>>>(w2, w2b, HID * KW);
  binarize_kernel<<<(HID * KW + 255) / 256, 256, 0, stream>>>(w3, w3b, HID * KW);
  binarize_kernel<<<(DOUT * KW + 255) / 256, 256, 0, stream>>>(w4, w4b, DOUT * KW);
  binarize_w1_kernel<<<(HID * 25 + 255) / 256, 256, 0, stream>>>(w1, w1b);
  convert_x_kernel<<<(BATCH * 50) / 256, 256, 0, stream>>>(x, xhl);

  gemm1_mfma_kernel<<<(BATCH / 128) * (HID / 256), 256, 0, stream>>>(
      xhl, (const uint8_t*)w1b, b1, g1, be1, m1, v1, bits1, cnt, list);
  fixup_chain_kernel<<<512, 256, 0, stream>>>(
      x, w1, b1, g1, be1, m1, v1, bits1, cnt, list);

  bitgemm_kernel<<<(BATCH / 128) * (HID / 128), 256, 0, stream>>>(
      bits1, w2b, b2, g2, be2, m2, v2, bits2);
  bitgemm_kernel<<<(BATCH / 128) * (HID / 128), 256, 0, stream>>>(
      bits2, w3b, b3, g3, be3, m3, v3, bits1);

  final_kernel<<<BATCH / 4, 256, 0, stream>>>(bits1, w4b, b4, out);
}

// Round 8
// 2499.435 us; speedup vs baseline: 1.0661x; 1.0661x over previous
//
#include <hip/hip_runtime.h>
#include <hip/hip_bf16.h>
#include <stdint.h>
#include <math.h>

#define BATCH 16384
#define DIN   784
#define HID   4096
#define DOUT  10
#define KW    128            // HID/32 words per row
#define KP    1600           // split-K: hi[0,784) lo[784,1568) pad[1568,1600)
#define CAP   1048576
#define BN_EPS 1e-5
#define TAU   0.05f          // verified R5/R6: |h_mfma - h_chain| << TAU

// ---------------- workspace layout (bytes) ----------------
constexpr size_t SZ_BITS   = (size_t)BATCH * KW * 4;     // 8 MB
constexpr size_t OFF_BITS1 = 0;
constexpr size_t OFF_BITS2 = OFF_BITS1 + SZ_BITS;
constexpr size_t OFF_W2B   = OFF_BITS2 + SZ_BITS;
constexpr size_t OFF_W3B   = OFF_W2B + (size_t)HID * KW * 4;
constexpr size_t OFF_W4B   = OFF_W3B + (size_t)HID * KW * 4;
constexpr size_t OFF_CNT   = OFF_W4B + 8192;
constexpr size_t OFF_LIST  = OFF_CNT + 256;
constexpr size_t OFF_XHL   = (OFF_LIST + (size_t)CAP * 4 + 255) & ~(size_t)255;
constexpr size_t OFF_WSD   = OFF_XHL + (size_t)BATCH * KP * 2;   // 52.4 MB
// Wsd: 4096*1600*2 = 13.1 MB

typedef __attribute__((ext_vector_type(8))) short frag8;   // 8 bf16 (4 VGPRs)
typedef __attribute__((ext_vector_type(4))) float f32x4;   // MFMA accum

typedef const __attribute__((address_space(1))) uint32_t guint;
typedef __attribute__((address_space(3))) uint32_t luint;

__device__ __forceinline__ void load16_to_lds(const void* g, void* l) {
  __builtin_amdgcn_global_load_lds((guint*)g, (luint*)l, 16, 0, 0);
}

__device__ __forceinline__ unsigned short f2bf_bits(float x) {
  __hip_bfloat16 h = __float2bfloat16(x);   // RNE
  return *reinterpret_cast<unsigned short*>(&h);
}
__device__ __forceinline__ float bf2f(unsigned short b) {
  union { unsigned int u; float f; } c;
  c.u = ((unsigned int)b) << 16;
  return c.f;
}

__global__ void zero_cnt_kernel(int* cnt) {
  if (threadIdx.x == 0) *cnt = 0;
}

// binarize row-major contiguous fp32 -> bitmask words
__global__ __launch_bounds__(256) void binarize_kernel(
    const float* __restrict__ w, uint32_t* __restrict__ bits, int nwords) {
  int t = blockIdx.x * 256 + threadIdx.x;
  if (t >= nwords) return;
  const float* p = w + (size_t)t * 32;
  uint32_t word = 0;
#pragma unroll
  for (int q = 0; q < 8; ++q) {
    float4 v = *(const float4*)(p + q * 4);
    word |= (uint32_t)(v.x >= 0.f) << (4 * q + 0);
    word |= (uint32_t)(v.y >= 0.f) << (4 * q + 1);
    word |= (uint32_t)(v.z >= 0.f) << (4 * q + 2);
    word |= (uint32_t)(v.w >= 0.f) << (4 * q + 3);
  }
  bits[t] = word;
}

// X -> bf16 hi/lo split, row layout [hi 0..783 | lo 784..1567 | zero pad ..1599]
__global__ __launch_bounds__(256) void convert_x_kernel(
    const float* __restrict__ X, short* __restrict__ Xhl) {
  int idx = blockIdx.x * 256 + threadIdx.x;      // BATCH*50 = 819200 exact
  int row = idx / 50, kq = idx - row * 50;
  short* orow = Xhl + (size_t)row * KP;
  if (kq < 49) {
    const float* p = X + (size_t)row * DIN + kq * 16;
    short hi[16], lo[16];
#pragma unroll
    for (int q = 0; q < 4; ++q) {
      float4 v = *(const float4*)(p + q * 4);
      float vv[4] = {v.x, v.y, v.z, v.w};
#pragma unroll
      for (int e = 0; e < 4; ++e) {
        unsigned short h = f2bf_bits(vv[e]);
        hi[q * 4 + e] = (short)h;
        lo[q * 4 + e] = (short)f2bf_bits(vv[e] - bf2f(h));
      }
    }
    *(uint4*)(orow + kq * 16)           = *(uint4*)&hi[0];
    *(uint4*)(orow + kq * 16 + 8)       = *(uint4*)&hi[8];
    *(uint4*)(orow + 784 + kq * 16)     = *(uint4*)&lo[0];
    *(uint4*)(orow + 784 + kq * 16 + 8) = *(uint4*)&lo[8];
  } else {
    uint4 z = {0, 0, 0, 0};
#pragma unroll
    for (int q = 0; q < 4; ++q) *(uint4*)(orow + 1568 + q * 8) = z;
  }
}

// W1 -> sign(+-1) bf16 duplicated in both K-halves, zero pad
__global__ __launch_bounds__(256) void convert_w_kernel(
    const float* __restrict__ W, short* __restrict__ Wsd) {
  int idx = blockIdx.x * 256 + threadIdx.x;      // HID*50 = 204800 exact
  int row = idx / 50, kq = idx - row * 50;
  short* orow = Wsd + (size_t)row * KP;
  if (kq < 49) {
    const float* p = W + (size_t)row * DIN + kq * 16;
    short s[16];
#pragma unroll
    for (int q = 0; q < 4; ++q) {
      float4 v = *(const float4*)(p + q * 4);
      s[q * 4 + 0] = (short)((v.x >= 0.f) ? 0x3F80 : 0xBF80);
      s[q * 4 + 1] = (short)((v.y >= 0.f) ? 0x3F80 : 0xBF80);
      s[q * 4 + 2] = (short)((v.z >= 0.f) ? 0x3F80 : 0xBF80);
      s[q * 4 + 3] = (short)((v.w >= 0.f) ? 0x3F80 : 0xBF80);
    }
    *(uint4*)(orow + kq * 16)           = *(uint4*)&s[0];
    *(uint4*)(orow + kq * 16 + 8)       = *(uint4*)&s[8];
    *(uint4*)(orow + 784 + kq * 16)     = *(uint4*)&s[0];
    *(uint4*)(orow + 784 + kq * 16 + 8) = *(uint4*)&s[8];
  } else {
    uint4 z = {0, 0, 0, 0};
#pragma unroll
    for (int q = 0; q < 4; ++q) *(uint4*)(orow + 1568 + q * 8) = z;
  }
}

// Layer 1: bf16 MFMA GEMM, R6 structure (global_load_lds 16B staging,
// 128x128 tile, BK=64, XOR-swizzled chunks -> 0 bank conflicts) with R7's
// XCD-affine mapping (xcd=bid&7 owns a 16-rb M-stripe; cb iterates fastest
// so each XCD's A-slices stay L2-resident; Wsd is L3-resident chip-wide).
__global__ __launch_bounds__(256) void gemm1_mfma_kernel(
    const short* __restrict__ Xhl, const short* __restrict__ Wsd,
    const float* __restrict__ Bv, const float* __restrict__ Gv,
    const float* __restrict__ BEv, const float* __restrict__ Mv,
    const float* __restrict__ Vv,
    uint32_t* __restrict__ bits_out, int* __restrict__ cnt,
    uint32_t* __restrict__ list) {
  __shared__ short Ah[128 * 64];            // 16 KB  [m][k-chunk swizzled]
  __shared__ short Bh[128 * 64];            // 16 KB  [n][k-chunk swizzled]
  __shared__ unsigned short PW16[128 * 8];  // 2 KB

  const int tid = threadIdx.x;
  const int bid = blockIdx.x;               // 4096 blocks
  const int xcd = bid & 7;
  const int t   = bid >> 3;                 // 0..511
  const int cb  = t & 31;                   // 0..31  fastest
  const int rb  = (xcd << 4) + (t >> 5);    // 0..127
  const int m0 = rb * 128, n0 = cb * 128;

  const int lane = tid & 63;
  const int w  = tid >> 6;            // wave 0..3
  const int wm = w & 1;               // row-half
  const int wn = w >> 1;              // col-half
  const int l15 = lane & 15;
  const int l4  = lane >> 4;          // 0..3

  f32x4 acc[4][4];
#pragma unroll
  for (int i = 0; i < 4; ++i)
#pragma unroll
    for (int j = 0; j < 4; ++j) acc[i][j] = (f32x4){0.f, 0.f, 0.f, 0.f};

  // staging: wave w covers rows [w*32, w*32+32) of both tiles.
  // lane -> row group (lane>>3), chunk (lane&7) XOR-swizzled by row&7 on the
  // GLOBAL side so LDS slot (row, c) holds global chunk c^(row&7).
  const int srow = lane >> 3;                    // 0..7
  const int schunk = (lane & 7) ^ srow;          // swizzled source chunk
  const char* gA = (const char*)(Xhl + (size_t)(m0 + w * 32) * KP)
                   + (size_t)srow * (KP * 2) + schunk * 16;
  const char* gB = (const char*)(Wsd + (size_t)(n0 + w * 32) * KP)
                   + (size_t)srow * (KP * 2) + schunk * 16;
  short* ldsA = &Ah[(w * 32) * 64];
  short* ldsB = &Bh[(w * 32) * 64];

  for (int s = 0; s < 25; ++s) {         // 25 slabs of BK=64 over KP=1600
#pragma unroll
    for (int rr = 0; rr < 4; ++rr) {
      load16_to_lds(gA + (size_t)rr * 8 * KP * 2, ldsA + rr * 8 * 64);
      load16_to_lds(gB + (size_t)rr * 8 * KP * 2, ldsB + rr * 8 * 64);
    }
    gA += 128;  gB += 128;               // advance 64 bf16
    __syncthreads();                     // drains vmcnt -> LDS valid
#pragma unroll
    for (int h = 0; h < 2; ++h) {        // two K=32 halves
      frag8 af[4], bf[4];
#pragma unroll
      for (int f = 0; f < 4; ++f) {
        const int ma = wm * 64 + f * 16 + l15;
        const int nb = wn * 64 + f * 16 + l15;
        const int ca = ((h * 4 + l4) ^ (l15 & 7)) * 8;
        af[f] = *(const frag8*)&Ah[ma * 64 + ca];
        bf[f] = *(const frag8*)&Bh[nb * 64 + ca];
      }
#pragma unroll
      for (int fm = 0; fm < 4; ++fm)
#pragma unroll
        for (int fn = 0; fn < 4; ++fn)
          acc[fm][fn] = __builtin_amdgcn_mfma_f32_16x16x32_bf16(
              af[fm], bf[fn], acc[fm][fn], 0, 0, 0);
    }
    __syncthreads();
  }

  // ---- epilogue: BN sign + borderline flag + ballot pack (R5/R6-verified) ----
#pragma unroll
  for (int fn = 0; fn < 4; ++fn) {
    const int gj = n0 + wn * 64 + fn * 16 + l15;
    const float  bj = Bv[gj];
    const double scale = (double)Gv[gj] / sqrt((double)Vv[gj] + BN_EPS);
    const double mj = (double)Mv[gj], bej = (double)BEv[gj];
    const double thr = (double)TAU * fabs(scale);
#pragma unroll
    for (int fm = 0; fm < 4; ++fm) {
#pragma unroll
      for (int r = 0; r < 4; ++r) {
        const int row_l = wm * 64 + fm * 16 + l4 * 4 + r;
        float hb = acc[fm][fn][r] + bj;            // f32, matches chain epilogue
        double bnd = ((double)hb - mj) * scale + bej;
        unsigned int bit = (bnd >= 0.0) ? 1u : 0u;
        unsigned long long mask = __ballot(bit);
        if (l15 == 0)
          PW16[row_l * 8 + (wn * 4 + fn)] =
              (unsigned short)(mask >> (l4 * 16));
        if (fabs(bnd) < thr) {
          int pos = atomicAdd(cnt, 1);
          if (pos < CAP)
            list[pos] = (uint32_t)((m0 + row_l) * HID + gj);
        }
      }
    }
  }
  __syncthreads();
  for (int t2 = tid; t2 < 512; t2 += 256) {
    int row = t2 >> 2, wc = t2 & 3;
    uint32_t word = (uint32_t)PW16[row * 8 + wc * 2] |
                    ((uint32_t)PW16[row * 8 + wc * 2 + 1] << 16);
    bits_out[(size_t)(m0 + row) * KW + (n0 >> 5) + wc] = word;
  }
}

// Recompute flagged layer-1 elements with the reference's EXACT semantics:
// sequential ascending-k single f32 FMA chain, then h + b in f32, then BN.
__global__ __launch_bounds__(256) void fixup_chain_kernel(
    const float* __restrict__ X, const float* __restrict__ W,
    const float* __restrict__ Bv, const float* __restrict__ Gv,
    const float* __restrict__ BEv, const float* __restrict__ Mv,
    const float* __restrict__ Vv,
    uint32_t* __restrict__ bits1, const int* __restrict__ cnt,
    const uint32_t* __restrict__ list) {
  int n = *cnt;
  if (n > CAP) n = CAP;
  for (int idx = blockIdx.x * 256 + threadIdx.x; idx < n;
       idx += gridDim.x * 256) {
    uint32_t code = list[idx];
    int i = code >> 12;
    int j = code & (HID - 1);
    const float* xr = X + (size_t)i * DIN;
    const float* wr = W + (size_t)j * DIN;
    float h = 0.f;
    for (int k = 0; k < DIN; k += 4) {     // strictly ascending k
      float4 xv = *(const float4*)(xr + k);
      float4 wv = *(const float4*)(wr + k);
      h = fmaf(xv.x, (wv.x >= 0.f) ? 1.f : -1.f, h);
      h = fmaf(xv.y, (wv.y >= 0.f) ? 1.f : -1.f, h);
      h = fmaf(xv.z, (wv.z >= 0.f) ? 1.f : -1.f, h);
      h = fmaf(xv.w, (wv.w >= 0.f) ? 1.f : -1.f, h);
    }
    float hb = h + Bv[j];
    double scale = (double)Gv[j] / sqrt((double)Vv[j] + BN_EPS);
    double bnd = ((double)hb - (double)Mv[j]) * scale + (double)BEv[j];
    uint32_t bit = (bnd >= 0.0) ? 1u : 0u;
    uint32_t* wpw = &bits1[(size_t)i * KW + (j >> 5)];
    uint32_t cur = (*wpw >> (j & 31)) & 1u;
    if (cur != bit) atomicXor(wpw, 1u << (j & 31));
  }
}

// Layers 2/3: +-1 x +-1 GEMM via XOR+popcount (exact). BN -> sign bits out.
// XCD swizzle: each XCD owns an rb stripe; W-bits (2 MB) stay L2-resident.
__global__ __launch_bounds__(256) void bitgemm_kernel(
    const uint32_t* __restrict__ Abits, const uint32_t* __restrict__ Wbits,
    const float* __restrict__ Bv, const float* __restrict__ Gv,
    const float* __restrict__ BEv, const float* __restrict__ Mv,
    const float* __restrict__ Vv, uint32_t* __restrict__ bits_out) {
  __shared__ uint32_t As[16 * 128];
  __shared__ uint32_t Bs[16 * 128];
  __shared__ unsigned int PW[128 * 4];

  const int tid = threadIdx.x;
  const int bid = blockIdx.x;                 // 4096 blocks
  const int xcd = bid & 7;
  const int t   = bid >> 3;                   // 0..511
  const int cb  = t & 31;
  const int rb  = xcd * 16 + (t >> 5);        // 0..127
  const int m0 = rb * 128, n0 = cb * 128;
  const int tx = tid & 15, ty = tid >> 4;

  int acc[8][8];
#pragma unroll
  for (int r = 0; r < 8; ++r)
#pragma unroll
    for (int c = 0; c < 8; ++c) acc[r][c] = 0;

  const int sr = tid >> 1;
  const int sk = (tid & 1) * 8;
  const uint32_t* arow = Abits + (size_t)(m0 + sr) * KW + sk;
  const uint32_t* wrow = Wbits + (size_t)(n0 + sr) * KW + sk;

  for (int w0 = 0; w0 < KW; w0 += 16) {
    uint4 a0 = *(const uint4*)(arow + w0);
    uint4 a1 = *(const uint4*)(arow + w0 + 4);
    uint4 b0 = *(const uint4*)(wrow + w0);
    uint4 b1 = *(const uint4*)(wrow + w0 + 4);
    __syncthreads();
    As[(sk + 0) * 128 + sr] = a0.x;  As[(sk + 1) * 128 + sr] = a0.y;
    As[(sk + 2) * 128 + sr] = a0.z;  As[(sk + 3) * 128 + sr] = a0.w;
    As[(sk + 4) * 128 + sr] = a1.x;  As[(sk + 5) * 128 + sr] = a1.y;
    As[(sk + 6) * 128 + sr] = a1.z;  As[(sk + 7) * 128 + sr] = a1.w;
    Bs[(sk + 0) * 128 + sr] = b0.x;  Bs[(sk + 1) * 128 + sr] = b0.y;
    Bs[(sk + 2) * 128 + sr] = b0.z;  Bs[(sk + 3) * 128 + sr] = b0.w;
    Bs[(sk + 4) * 128 + sr] = b1.x;  Bs[(sk + 5) * 128 + sr] = b1.y;
    Bs[(sk + 6) * 128 + sr] = b1.z;  Bs[(sk + 7) * 128 + sr] = b1.w;
    __syncthreads();
#pragma unroll
    for (int kk = 0; kk < 16; ++kk) {
      uint32_t a[8], b[8];
      *(uint4*)&a[0] = *(const uint4*)&As[kk * 128 + ty * 8];
      *(uint4*)&a[4] = *(const uint4*)&As[kk * 128 + ty * 8 + 4];
      *(uint4*)&b[0] = *(const uint4*)&Bs[kk * 128 + tx * 8];
      *(uint4*)&b[4] = *(const uint4*)&Bs[kk * 128 + tx * 8 + 4];
#pragma unroll
      for (int r = 0; r < 8; ++r)
#pragma unroll
        for (int c = 0; c < 8; ++c)
          acc[r][c] += __popc(a[r] ^ b[c]);
    }
  }

  uint32_t bm[8];
#pragma unroll
  for (int r = 0; r < 8; ++r) bm[r] = 0;
  for (int c = 0; c < 8; ++c) {
    const int j = n0 + tx * 8 + c;
    const double scale = (double)Gv[j] / sqrt((double)Vv[j] + BN_EPS);
    const double mj = (double)Mv[j], bej = (double)BEv[j], bj = (double)Bv[j];
#pragma unroll
    for (int r = 0; r < 8; ++r) {
      double h = (double)(HID - 2 * acc[r][c]) + bj;   // exact integer dot
      double bnd = (h - mj) * scale + bej;
      bm[r] |= (uint32_t)(bnd >= 0.0) << c;
    }
  }
  for (int t2 = tid; t2 < 512; t2 += 256) PW[t2] = 0u;
  __syncthreads();
#pragma unroll
  for (int r = 0; r < 8; ++r)
    atomicOr(&PW[(ty * 8 + r) * 4 + (tx >> 2)], bm[r] << (8 * (tx & 3)));
  __syncthreads();
  for (int w = tid; w < 512; w += 256) {
    int row = w >> 2, wc = w & 3;
    bits_out[(size_t)(m0 + row) * KW + (n0 >> 5) + wc] = PW[row * 4 + wc];
  }
}

// Layer 4 (10 outputs) + log_softmax. One wave per batch row.
__global__ __launch_bounds__(256) void final_kernel(
    const uint32_t* __restrict__ xbits, const uint32_t* __restrict__ w4b,
    const float* __restrict__ b4, float* __restrict__ out) {
  __shared__ uint32_t Ws[DOUT * KW];   // 5 KB
  const int tid = threadIdx.x;
  for (int t = tid; t < DOUT * KW; t += 256) Ws[t] = w4b[t];
  __syncthreads();
  const int lane = tid & 63;
  const int i = blockIdx.x * 4 + (tid >> 6);
  const uint32_t x0 = xbits[(size_t)i * KW + lane];
  const uint32_t x1 = xbits[(size_t)i * KW + 64 + lane];
  int cnt[DOUT];
#pragma unroll
  for (int j = 0; j < DOUT; ++j)
    cnt[j] = __popc(x0 ^ Ws[j * KW + lane]) + __popc(x1 ^ Ws[j * KW + 64 + lane]);
#pragma unroll
  for (int j = 0; j < DOUT; ++j)
#pragma unroll
    for (int off = 32; off; off >>= 1) cnt[j] += __shfl_xor(cnt[j], off);
  double logit[DOUT];
  double mx = -1e300;
#pragma unroll
  for (int j = 0; j < DOUT; ++j) {
    logit[j] = (double)(HID - 2 * cnt[j]) + (double)b4[j];
    mx = fmax(mx, logit[j]);
  }
  double s = 0.0;
#pragma unroll
  for (int j = 0; j < DOUT; ++j) s += exp(logit[j] - mx);
  double lse = log(s) + mx;
  if (lane < DOUT)
    out[(size_t)i * DOUT + lane] = (float)(logit[lane] - lse);
}

extern "C" void kernel_launch(void* const* d_in, const int* in_sizes, int n_in,
                              void* d_out, int out_size, void* d_ws, size_t ws_size,
                              hipStream_t stream) {
  const float* x   = (const float*)d_in[0];
  const float* w1  = (const float*)d_in[1];
  const float* b1  = (const float*)d_in[2];
  const float* g1  = (const float*)d_in[3];
  const float* be1 = (const float*)d_in[4];
  const float* m1  = (const float*)d_in[5];
  const float* v1  = (const float*)d_in[6];
  const float* w2  = (const float*)d_in[7];
  const float* b2  = (const float*)d_in[8];
  const float* g2  = (const float*)d_in[9];
  const float* be2 = (const float*)d_in[10];
  const float* m2  = (const float*)d_in[11];
  const float* v2  = (const float*)d_in[12];
  const float* w3  = (const float*)d_in[13];
  const float* b3  = (const float*)d_in[14];
  const float* g3  = (const float*)d_in[15];
  const float* be3 = (const float*)d_in[16];
  const float* m3  = (const float*)d_in[17];
  const float* v3  = (const float*)d_in[18];
  const float* w4  = (const float*)d_in[19];
  const float* b4  = (const float*)d_in[20];

  char* ws = (char*)d_ws;
  uint32_t* bits1 = (uint32_t*)(ws + OFF_BITS1);
  uint32_t* bits2 = (uint32_t*)(ws + OFF_BITS2);
  uint32_t* w2b   = (uint32_t*)(ws + OFF_W2B);
  uint32_t* w3b   = (uint32_t*)(ws + OFF_W3B);
  uint32_t* w4b   = (uint32_t*)(ws + OFF_W4B);
  int*      cnt   = (int*)(ws + OFF_CNT);
  uint32_t* list  = (uint32_t*)(ws + OFF_LIST);
  short*    xhl   = (short*)(ws + OFF_XHL);
  short*    wsd   = (short*)(ws + OFF_WSD);
  float*    out   = (float*)d_out;

  zero_cnt_kernel<<<1, 64, 0, stream>>>(cnt);
  binarize_kernel<<<(HID * KW + 255) / 256, 256, 0, stream>>>(w2, w2b, HID * KW);
  binarize_kernel<<<(HID * KW + 255) / 256, 256, 0, stream>>>(w3, w3b, HID * KW);
  binarize_kernel<<<(DOUT * KW + 255) / 256, 256, 0, stream>>>(w4, w4b, DOUT * KW);
  convert_x_kernel<<<(BATCH * 50) / 256, 256, 0, stream>>>(x, xhl);
  convert_w_kernel<<<(HID * 50) / 256, 256, 0, stream>>>(w1, wsd);

  gemm1_mfma_kernel<<<(BATCH / 128) * (HID / 128), 256, 0, stream>>>(
      xhl, wsd, b1, g1, be1, m1, v1, bits1, cnt, list);
  fixup_chain_kernel<<<512, 256, 0, stream>>>(
      x, w1, b1, g1, be1, m1, v1, bits1, cnt, list);

  bitgemm_kernel<<<(BATCH / 128) * (HID / 128), 256, 0, stream>>>(
      bits1, w2b, b2, g2, be2, m2, v2, bits2);
  bitgemm_kernel<<<(BATCH / 128) * (HID / 128), 256, 0, stream>>>(
      bits2, w3b, b3, g3, be3, m3, v3, bits1);

  final_kernel<<<BATCH / 4, 256, 0, stream>>>(bits1, w4b, b4, out);
}